// Round 1
// baseline (876.272 us; speedup 1.0000x reference)
//
#include <hip/hip_runtime.h>
#include <stdint.h>

#define B_    128
#define S_    256
#define EMB_  300
#define HID_  256
#define TAGS_ 50
#define KPAD  320           // EMB padded to multiple of 32
#define NROWS (B_ * S_)     // 32768, row r = s*128 + b
#define GF    (4 * HID_)    // 1024 gate cols per direction
#define NCOLS (2 * GF)      // 2048 (fwd | bwd)

typedef __bf16 bf16x8 __attribute__((ext_vector_type(8)));
typedef float  f32x4  __attribute__((ext_vector_type(4)));
typedef unsigned int u32x4 __attribute__((ext_vector_type(4)));
typedef unsigned long long u64x2 __attribute__((ext_vector_type(2)));
typedef int    i32x8  __attribute__((ext_vector_type(8)));

__device__ __forceinline__ unsigned short f2bf(float f) {
    unsigned int u = __float_as_uint(f);
    unsigned int r = (u + 0x7fffu + ((u >> 16) & 1u)) >> 16;  // RNE
    return (unsigned short)r;
}
__device__ __forceinline__ bf16x8 ldb8(const unsigned short* p) {
    u32x4 v = *reinterpret_cast<const u32x4*>(p);
    return __builtin_bit_cast(bf16x8, v);
}
// fast sigmoid: v_exp_f32 + v_rcp_f32 (avoids IEEE div expansion; ~1e-7 err)
__device__ __forceinline__ float sigf(float x) {
    return __builtin_amdgcn_rcpf(1.0f + __builtin_amdgcn_exp2f(x * -1.44269504f));
}
// element q of an f32x4 without dynamic vector indexing (2 cndmask chains)
__device__ __forceinline__ float selq(f32x4 v, int q) {
    float a = (q & 1) ? v[1] : v[0];
    float b = (q & 1) ? v[3] : v[2];
    return (q & 2) ? b : a;
}
// unpack u64 of 4 bf16 (batches 0..3) into f32x4 accumulator-init vector.
// bf16->f32 is just <<16; elements use compile-time shifts only.
__device__ __forceinline__ f32x4 xz2acc(unsigned long long v) {
    unsigned int lo = (unsigned int)v, hi = (unsigned int)(v >> 32);
    f32x4 r;
    r[0] = __uint_as_float(lo << 16);
    r[1] = __uint_as_float(lo & 0xffff0000u);
    r[2] = __uint_as_float(hi << 16);
    r[3] = __uint_as_float(hi & 0xffff0000u);
    return r;
}

// ---------------- K0a: embedding gather -> bf16, K-padded -------------------
__global__ void k_gather_x(const int* __restrict__ tokens, const float* __restrict__ emb,
                           unsigned short* __restrict__ X16) {
    int r = blockIdx.x;            // r = s*128 + b
    int k = threadIdx.x;           // 0..319
    int b = r & 127, s = r >> 7;
    int tok = tokens[b * S_ + s];
    float v = (k < EMB_) ? emb[(long)tok * EMB_ + k] : 0.0f;
    X16[(long)r * KPAD + k] = f2bf(v);
}

// ---------------- K0b: Wx (f|b) -> transposed bf16 [2048][320] --------------
__global__ void k_prep_w(const float* __restrict__ Wx_f, const float* __restrict__ Wx_b,
                         unsigned short* __restrict__ W16T) {
    int c = blockIdx.x;            // 0..2047
    int k = threadIdx.x;           // 0..319
    float v = 0.0f;
    if (k < EMB_) v = (c < GF) ? Wx_f[k * GF + c] : Wx_b[k * GF + (c - GF)];
    W16T[c * KPAD + k] = f2bf(v);
}

// ---------------- K0c: Wd -> transposed bf16 [64][512] ----------------------
__global__ void k_prep_wd(const float* __restrict__ Wd, unsigned short* __restrict__ WdT16) {
    int c = blockIdx.x;            // 0..63
    int k = threadIdx.x;           // 0..511
    float v = (c < TAGS_) ? Wd[k * TAGS_ + c] : 0.0f;
    WdT16[c * 512 + k] = f2bf(v);
}

// ---------------- K0d: Wh -> packed bf16 [2 dir][4 sl][256 c][256 k] --------
__global__ void k_prep_wh(const float* __restrict__ Wh_f, const float* __restrict__ Wh_b,
                          unsigned short* __restrict__ WhP) {
    int row = blockIdx.x;          // 0..2047 = (d*4+sl)*256 + c
    int k = threadIdx.x;           // 0..255
    int d = row >> 10, sl = (row >> 8) & 3, c = row & 255;
    int gate = c >> 6, jrel = c & 63;
    const float* Wh = d ? Wh_b : Wh_f;
    WhP[(long)row * 256 + k] = f2bf(Wh[k * GF + gate * HID_ + sl * 64 + jrel]);
}

// ---------------- K0e: Wh gates i,f,o -> fp8 e4m3 [2 dir][3 g][256 j][256 k]-
__global__ void k_prep_wh8(const float* __restrict__ Wh_f, const float* __restrict__ Wh_b,
                           unsigned char* __restrict__ WhP8) {
    int row = blockIdx.x;          // 0..1535 = (d*3+gi)*256 + j
    int k = threadIdx.x;           // 0..255
    int d = row / 768, rr = row - d * 768, gi = rr >> 8, j = rr & 255;
    int ga = (gi == 2) ? 3 : gi;   // i=0, f=1, o=3
    const float* Wh = d ? Wh_b : Wh_f;
    float v = Wh[k * GF + ga * HID_ + j];
    int p = __builtin_amdgcn_cvt_pk_fp8_f32(v, 0.0f, 0, false);
    WhP8[(long)row * 256 + k] = (unsigned char)(p & 0xff);
}

// ---------------- K1: xz = X @ Wx + b  (MFMA, LDS-free) ---------------------
// xzP gate-major layout: u64 idx = ((s*16+g16)*64 + gate*16 + u16)*64 + b4*16 + j
// (u64 packs 4 batches b4*4+{0..3} as bf16). Producer stores are 512 B/wave
// contiguous; consumer reads stay 128 B/quad coalesced.
__global__ __launch_bounds__(256) void k_gemm_xz(
    const unsigned short* __restrict__ X16, const unsigned short* __restrict__ W16T,
    const float* __restrict__ b_f, const float* __restrict__ b_b,
    unsigned long long* __restrict__ xzP) {
    int w = threadIdx.x >> 6, lane = threadIdx.x & 63;
    int quad = lane >> 4, l16 = lane & 15;
    int m0 = blockIdx.x * 128 + w * 32;
    int n0 = blockIdx.y * 128;
    f32x4 acc[2][8];
#pragma unroll
    for (int mt = 0; mt < 2; ++mt)
#pragma unroll
        for (int nt = 0; nt < 8; ++nt) acc[mt][nt] = (f32x4){0.f, 0.f, 0.f, 0.f};

    int koff = quad * 8;
#pragma unroll
    for (int ks = 0; ks < 10; ++ks) {
        int k0 = ks * 32 + koff;
        bf16x8 a[2], bb[8];
#pragma unroll
        for (int mt = 0; mt < 2; ++mt)
            a[mt] = ldb8(X16 + (long)(m0 + mt * 16 + l16) * KPAD + k0);
#pragma unroll
        for (int nt = 0; nt < 8; ++nt)
            bb[nt] = ldb8(W16T + (long)(n0 + nt * 16 + l16) * KPAD + k0);
#pragma unroll
        for (int mt = 0; mt < 2; ++mt)
#pragma unroll
            for (int nt = 0; nt < 8; ++nt)
                acc[mt][nt] = __builtin_amdgcn_mfma_f32_16x16x32_bf16(a[mt], bb[nt], acc[mt][nt], 0, 0, 0);
    }
    int s = blockIdx.x;            // m>>7
#pragma unroll
    for (int mt = 0; mt < 2; ++mt) {
        int grp = w * 2 + mt;      // (b>>4)
#pragma unroll
        for (int nt = 0; nt < 8; ++nt) {
            int col = n0 + nt * 16 + l16;
            int dir = col >> 10, cc = col & 1023;
            int gate = cc >> 8, u16 = (cc & 255) >> 4;
            float bias = dir ? b_b[cc] : b_f[cc];
            unsigned long long pk = 0;
#pragma unroll
            for (int r = 0; r < 4; ++r)
                pk |= (unsigned long long)f2bf(acc[mt][nt][r] + bias) << (16 * r);
            long idx8 = ((long)(s * 16 + dir * 8 + grp)) * 4096 +
                        (gate * 16 + u16) * 64 + quad * 16 + l16;
            xzP[idx8] = pk;
        }
    }
}

// ---------------- K2: bidirectional LSTM recurrence, single-CU chains -------
// 64 blocks = 2 dir x 32 batch-groups(4). 512 threads, 2 waves/SIMD.
// Wh register-pinned: g bf16 (64 VGPR), i/f/o fp8 as K=128 scaled-MFMA
// fragments (96 VGPR). Changes this round:
//  - xz folded into MFMA C-init (f32x4 unpack, compile-time shifts) -- kills
//    the runtime 64-bit bfext shifts + adds (~40 VALU/lane/step).
//  - 2-step-ahead double-buffered xz prefetch (named bufs A/B, loop unroll x2
//    so all buffer indices are compile-time -> no scratch).
//  - sigmoid via v_exp_f32 + v_rcp_f32 (no IEEE div expansion on the c chain).
//  - h pair packed with v_cvt_pk_bf16_f32 + one cvt_pk_fp8 per pair.
// Barrier stays "s_waitcnt lgkmcnt(0); s_barrier" -- NO vmcnt drain.
__global__ __launch_bounds__(512, 2) void k_recurrence(
    const unsigned short* __restrict__ WhP, const unsigned char* __restrict__ WhP8,
    const unsigned long long* __restrict__ xzP, unsigned short* __restrict__ hcat16) {
    __shared__ __align__(16) unsigned char lds[6656];
    const int HB = 0, H8 = 4352;   // hb: 2 x 4 x 544 B; h8: 2 x 4 x 288 B
    int tid = threadIdx.x;
    int w = tid >> 6, lane = tid & 63, quad = lane >> 4, l16 = lane & 15;
    int blk = blockIdx.x;
    int d = blk >> 5, bg4 = blk & 31;
    int g16 = d * 8 + (bg4 >> 2), kq = bg4 & 3;
    int a3 = l16 & 3;

    // g-gate bf16 weight fragments, register-pinned (64 VGPR)
    u32x4 whg[2][8];
#pragma unroll
    for (int g2 = 0; g2 < 2; ++g2) {
        int j = 16 * (2 * w + g2) + l16;
        int sl = j >> 6, jrel = j & 63;
        const unsigned short* src = WhP + ((long)((d * 4 + sl) * 256 + 128 + jrel)) * 256;
#pragma unroll
        for (int kt = 0; kt < 8; ++kt) {
            u32x4 v = *reinterpret_cast<const u32x4*>(src + kt * 32 + quad * 8);
            asm volatile("" : "+v"(v));
            whg[g2][kt] = v;
        }
    }
    // i/f/o fp8 K=128 scaled-MFMA B fragments, register-pinned (96 VGPR)
    i32x8 wh8s[3][2][2];
#pragma unroll
    for (int gi = 0; gi < 3; ++gi)
#pragma unroll
        for (int g2 = 0; g2 < 2; ++g2)
#pragma unroll
            for (int kt2 = 0; kt2 < 2; ++kt2) {
                const unsigned char* wp8 = WhP8 +
                    ((long)((d * 3 + gi) * 256 + 16 * (2 * w + g2) + l16)) * 256 +
                    kt2 * 128 + quad * 32;
                i32x8 v = *reinterpret_cast<const i32x8*>(wp8);
                asm volatile("" : "+v"(v));
                wh8s[gi][g2][kt2] = v;
            }

    float c2[2] = {0.f, 0.f};

    // 2-step-ahead prefetch buffers (named -> static register allocation)
    unsigned long long xzA[2][4], xzB[2][4];
    {
        int s0 = d ? 255 : 0;
        const unsigned long long* p0 = xzP + ((long)(s0 * 16 + g16)) * 4096;
        int s1 = d ? 254 : 1;
        const unsigned long long* p1 = xzP + ((long)(s1 * 16 + g16)) * 4096;
#pragma unroll
        for (int g2 = 0; g2 < 2; ++g2)
#pragma unroll
            for (int ga = 0; ga < 4; ++ga) {
                xzA[g2][ga] = p0[(ga * 16 + 2 * w + g2) * 64 + kq * 16 + l16];
                xzB[g2][ga] = p1[(ga * 16 + 2 * w + g2) * 64 + kq * 16 + l16];
            }
    }

#define STEP(T, BUF, PB) do {                                                   \
    const int t_ = (T);                                                         \
    int s_ = d ? (255 - t_) : t_;                                               \
    f32x4 accg[2], acc8[3][2];                                                  \
    /* accumulator init = xz addends (C-row m -> batch m&3 == element r) */     \
    _Pragma("unroll")                                                           \
    for (int g2 = 0; g2 < 2; ++g2) {                                            \
        acc8[0][g2] = xz2acc(BUF[g2][0]);                                       \
        acc8[1][g2] = xz2acc(BUF[g2][1]);                                       \
        accg[g2]    = xz2acc(BUF[g2][2]);                                       \
        acc8[2][g2] = xz2acc(BUF[g2][3]);                                       \
    }                                                                           \
    /* prefetch step T+2 into the just-freed buffer (2-step slack > HBM lat) */ \
    {                                                                           \
        int sn_ = d ? (s_ >= 2 ? s_ - 2 : 0) : (s_ <= 253 ? s_ + 2 : 255);      \
        const unsigned long long* pn_ = xzP + ((long)(sn_ * 16 + g16)) * 4096;  \
        _Pragma("unroll")                                                       \
        for (int g2 = 0; g2 < 2; ++g2)                                          \
            _Pragma("unroll")                                                   \
            for (int ga = 0; ga < 4; ++ga)                                      \
                BUF[g2][ga] = pn_[(ga * 16 + 2 * w + g2) * 64 + kq * 16 + l16]; \
    }                                                                           \
    if (t_ > 0) {                                                               \
        _Pragma("unroll")                                                       \
        for (int kt = 0; kt < 8; ++kt) {                                        \
            bf16x8 A = ldb8(reinterpret_cast<const unsigned short*>(            \
                lds + HB + ((PB) ^ 1) * 2176 + a3 * 544 + kt * 64 + quad * 16));\
            _Pragma("unroll")                                                   \
            for (int g2 = 0; g2 < 2; ++g2)                                      \
                accg[g2] = __builtin_amdgcn_mfma_f32_16x16x32_bf16(             \
                    A, __builtin_bit_cast(bf16x8, whg[g2][kt]), accg[g2], 0, 0, 0); \
        }                                                                       \
        _Pragma("unroll")                                                       \
        for (int kt2 = 0; kt2 < 2; ++kt2) {                                     \
            i32x8 A8 = *reinterpret_cast<const i32x8*>(                         \
                lds + H8 + ((PB) ^ 1) * 1152 + a3 * 288 + kt2 * 128 + quad * 32); \
            _Pragma("unroll")                                                   \
            for (int g2 = 0; g2 < 2; ++g2)                                      \
                _Pragma("unroll")                                               \
                for (int gi = 0; gi < 3; ++gi)                                  \
                    acc8[gi][g2] = __builtin_amdgcn_mfma_scale_f32_16x16x128_f8f6f4( \
                        A8, wh8s[gi][g2][kt2], acc8[gi][g2], 0, 0, 0, 0x7F, 0, 0x7F); \
        }                                                                       \
    }                                                                           \
    float h0_, h1_;                                                             \
    {                                                                           \
        float zi = selq(acc8[0][0], quad), zf = selq(acc8[1][0], quad);         \
        float zg = selq(accg[0], quad),    zo = selq(acc8[2][0], quad);         \
        float c = sigf(zf) * c2[0] + sigf(zi) * fmaxf(zg, 0.0f);                \
        c2[0] = c;                                                              \
        h0_ = sigf(zo) * fmaxf(c, 0.0f);                                        \
    }                                                                           \
    {                                                                           \
        float zi = selq(acc8[0][1], quad), zf = selq(acc8[1][1], quad);         \
        float zg = selq(accg[1], quad),    zo = selq(acc8[2][1], quad);         \
        float c = sigf(zf) * c2[1] + sigf(zi) * fmaxf(zg, 0.0f);                \
        c2[1] = c;                                                              \
        h1_ = sigf(zo) * fmaxf(c, 0.0f);                                        \
    }                                                                           \
    unsigned int hbpk_;                                                         \
    asm("v_cvt_pk_bf16_f32 %0, %1, %2" : "=v"(hbpk_) : "v"(h0_), "v"(h1_));     \
    unsigned short lo16_ = (unsigned short)hbpk_;                               \
    unsigned short hi16_ = (unsigned short)(hbpk_ >> 16);                       \
    int col0_ = 32 * w + l16;                                                   \
    *reinterpret_cast<unsigned short*>(lds + HB + (PB) * 2176 + quad * 544 + col0_ * 2)      = lo16_; \
    *reinterpret_cast<unsigned short*>(lds + HB + (PB) * 2176 + quad * 544 + col0_ * 2 + 32) = hi16_; \
    int p8_ = __builtin_amdgcn_cvt_pk_fp8_f32(h0_, h1_, 0, false);              \
    *(lds + H8 + (PB) * 1152 + quad * 288 + col0_)      = (unsigned char)(p8_ & 0xff);        \
    *(lds + H8 + (PB) * 1152 + quad * 288 + col0_ + 16) = (unsigned char)((p8_ >> 8) & 0xff); \
    unsigned short* hc_ = hcat16 + ((long)(bg4 * 4 + quad) * S_ + s_) * 512 + d * HID_ + col0_; \
    hc_[0]  = lo16_;                                                            \
    hc_[16] = hi16_;                                                            \
    /* LDS-only barrier: no vmcnt drain (stores + prefetch stay in flight) */   \
    asm volatile("s_waitcnt lgkmcnt(0)\n\ts_barrier" ::: "memory");             \
} while (0)

    for (int t2 = 0; t2 < 128; ++t2) {
        STEP(2 * t2,     xzA, 0);
        STEP(2 * t2 + 1, xzB, 1);
    }
#undef STEP
}

// ---------------- K3: logits = hcat @ Wd  (MFMA, N padded to 64) ------------
__global__ __launch_bounds__(256) void k_gemm_logits(
    const unsigned short* __restrict__ hcat16, const unsigned short* __restrict__ WdT16,
    float* __restrict__ logits) {
    int w = threadIdx.x >> 6, lane = threadIdx.x & 63;
    int quad = lane >> 4, l16 = lane & 15;
    int m0 = blockIdx.x * 128 + w * 32;
    f32x4 acc[2][4];
#pragma unroll
    for (int mt = 0; mt < 2; ++mt)
#pragma unroll
        for (int nt = 0; nt < 4; ++nt) acc[mt][nt] = (f32x4){0.f, 0.f, 0.f, 0.f};
#pragma unroll
    for (int ks = 0; ks < 16; ++ks) {
        int k0 = ks * 32 + quad * 8;
        bf16x8 a[2], bb[4];
#pragma unroll
        for (int mt = 0; mt < 2; ++mt)
            a[mt] = ldb8(hcat16 + (long)(m0 + mt * 16 + l16) * 512 + k0);
#pragma unroll
        for (int nt = 0; nt < 4; ++nt)
            bb[nt] = ldb8(WdT16 + (long)(nt * 16 + l16) * 512 + k0);
#pragma unroll
        for (int mt = 0; mt < 2; ++mt)
#pragma unroll
            for (int nt = 0; nt < 4; ++nt)
                acc[mt][nt] = __builtin_amdgcn_mfma_f32_16x16x32_bf16(a[mt], bb[nt], acc[mt][nt], 0, 0, 0);
    }
#pragma unroll
    for (int mt = 0; mt < 2; ++mt)
#pragma unroll
        for (int nt = 0; nt < 4; ++nt) {
            int rbase = m0 + mt * 16 + quad * 4;
            int col = nt * 16 + l16;
#pragma unroll
            for (int r = 0; r < 4; ++r)
                logits[(long)(rbase + r) * 64 + col] = acc[mt][nt][r];
        }
}

// ---------------- K4: +bd, softmax over 50 tags (one wave per row) ----------
__global__ __launch_bounds__(256) void k_softmax(const float* __restrict__ logits,
                                                 const float* __restrict__ bd,
                                                 float* __restrict__ out) {
    int w = threadIdx.x >> 6, lane = threadIdx.x & 63;
    long r = (long)blockIdx.x * 4 + w;
    float x = (lane < TAGS_) ? logits[r * 64 + lane] + bd[lane] : -3.0e38f;
    float m = x;
#pragma unroll
    for (int off = 32; off >= 1; off >>= 1) m = fmaxf(m, __shfl_xor(m, off, 64));
    float e = (lane < TAGS_) ? __expf(x - m) : 0.0f;
    float ssum = e;
#pragma unroll
    for (int off = 32; off >= 1; off >>= 1) ssum += __shfl_xor(ssum, off, 64);
    if (lane < TAGS_) out[r * TAGS_ + lane] = e / ssum;
}

extern "C" void kernel_launch(void* const* d_in, const int* in_sizes, int n_in,
                              void* d_out, int out_size, void* d_ws, size_t ws_size,
                              hipStream_t stream) {
    (void)in_sizes; (void)n_in; (void)out_size; (void)ws_size;
    const int*   tokens = (const int*)  d_in[0];
    const float* emb    = (const float*)d_in[1];
    const float* Wx_f   = (const float*)d_in[2];
    const float* Wh_f   = (const float*)d_in[3];
    const float* b_f    = (const float*)d_in[4];
    const float* Wx_b   = (const float*)d_in[5];
    const float* Wh_b   = (const float*)d_in[6];
    const float* b_b    = (const float*)d_in[7];
    const float* Wd     = (const float*)d_in[8];
    const float* bd     = (const float*)d_in[9];
    float* out = (float*)d_out;

    // workspace layout (bytes): total 190,119,936
    uint8_t* w = (uint8_t*)d_ws;
    unsigned short* X16    = (unsigned short*)(w);                  // 20,971,520 (dead after K1)
    // aliases inside X16's region, used only after K1:
    unsigned short* WhP    = (unsigned short*)(w);                  //  1,048,576
    unsigned char*  WhP8   = (unsigned char*)(w + 1048576);         //    393,216
    unsigned short* W16T   = (unsigned short*)(w + 20971520);       //  1,310,720
    unsigned short* WdT16  = (unsigned short*)(w + 22282240);       //     65,536
    unsigned long long* xzP = (unsigned long long*)(w + 22347776);  // 134,217,728
    unsigned short* hcat16 = (unsigned short*)(w + 156565504);      //  33,554,432
    float*          logits = (float*)(w + 22347776);                // alias xzP (dead after K2)

    k_gather_x  <<<dim3(NROWS),     dim3(KPAD), 0, stream>>>(tokens, emb, X16);
    k_prep_w    <<<dim3(NCOLS),     dim3(KPAD), 0, stream>>>(Wx_f, Wx_b, W16T);
    k_prep_wd   <<<dim3(64),        dim3(512),  0, stream>>>(Wd, WdT16);
    k_gemm_xz   <<<dim3(256, 16),   dim3(256),  0, stream>>>(X16, W16T, b_f, b_b, xzP);
    // X16 region now dead -> build WhP / WhP8 in it
    k_prep_wh   <<<dim3(2048),      dim3(256),  0, stream>>>(Wh_f, Wh_b, WhP);
    k_prep_wh8  <<<dim3(1536),      dim3(256),  0, stream>>>(Wh_f, Wh_b, WhP8);
    k_recurrence<<<dim3(64),        dim3(512),  0, stream>>>(WhP, WhP8, xzP, hcat16);
    k_gemm_logits<<<dim3(256),      dim3(256),  0, stream>>>(hcat16, WdT16, logits);
    k_softmax   <<<dim3(NROWS / 4), dim3(256),  0, stream>>>(logits, bd, out);
}

// Round 2
// 637.840 us; speedup vs baseline: 1.3738x; 1.3738x over previous
//
#include <hip/hip_runtime.h>
#include <stdint.h>

#define B_    128
#define S_    256
#define EMB_  300
#define HID_  256
#define TAGS_ 50
#define KPAD  320           // EMB padded to multiple of 32
#define NROWS (B_ * S_)     // 32768, row r = s*128 + b
#define GF    (4 * HID_)    // 1024 gate cols per direction
#define NCOLS (2 * GF)      // 2048 (fwd | bwd)

typedef __bf16 bf16x8 __attribute__((ext_vector_type(8)));
typedef float  f32x4  __attribute__((ext_vector_type(4)));
typedef unsigned int u32x4 __attribute__((ext_vector_type(4)));
typedef unsigned long long u64x2 __attribute__((ext_vector_type(2)));
typedef int    i32x8  __attribute__((ext_vector_type(8)));

__device__ __forceinline__ unsigned short f2bf(float f) {
    unsigned int u = __float_as_uint(f);
    unsigned int r = (u + 0x7fffu + ((u >> 16) & 1u)) >> 16;  // RNE
    return (unsigned short)r;
}
__device__ __forceinline__ bf16x8 ldb8(const unsigned short* p) {
    u32x4 v = *reinterpret_cast<const u32x4*>(p);
    return __builtin_bit_cast(bf16x8, v);
}
// fast sigmoid: v_exp_f32 + v_rcp_f32 (no IEEE div expansion; ~1ulp rcp err)
__device__ __forceinline__ float sigf(float x) {
    return __builtin_amdgcn_rcpf(1.0f + __builtin_amdgcn_exp2f(x * -1.44269504f));
}
// element q of an f32x4 without dynamic vector indexing (2 cndmask chains)
__device__ __forceinline__ float selq(f32x4 v, int q) {
    float a = (q & 1) ? v[1] : v[0];
    float b = (q & 1) ? v[3] : v[2];
    return (q & 2) ? b : a;
}
__device__ __forceinline__ float bfext(unsigned long long u, int sh) {
    return __uint_as_float((((unsigned int)(u >> sh)) & 0xffffu) << 16);
}

// ---------------- K0a: embedding gather -> bf16, K-padded -------------------
__global__ void k_gather_x(const int* __restrict__ tokens, const float* __restrict__ emb,
                           unsigned short* __restrict__ X16) {
    int r = blockIdx.x;            // r = s*128 + b
    int k = threadIdx.x;           // 0..319
    int b = r & 127, s = r >> 7;
    int tok = tokens[b * S_ + s];
    float v = (k < EMB_) ? emb[(long)tok * EMB_ + k] : 0.0f;
    X16[(long)r * KPAD + k] = f2bf(v);
}

// ---------------- K0b: Wx (f|b) -> transposed bf16 [2048][320] --------------
__global__ void k_prep_w(const float* __restrict__ Wx_f, const float* __restrict__ Wx_b,
                         unsigned short* __restrict__ W16T) {
    int c = blockIdx.x;            // 0..2047
    int k = threadIdx.x;           // 0..319
    float v = 0.0f;
    if (k < EMB_) v = (c < GF) ? Wx_f[k * GF + c] : Wx_b[k * GF + (c - GF)];
    W16T[c * KPAD + k] = f2bf(v);
}

// ---------------- K0c: Wd -> transposed bf16 [64][512] ----------------------
__global__ void k_prep_wd(const float* __restrict__ Wd, unsigned short* __restrict__ WdT16) {
    int c = blockIdx.x;            // 0..63
    int k = threadIdx.x;           // 0..511
    float v = (c < TAGS_) ? Wd[k * TAGS_ + c] : 0.0f;
    WdT16[c * 512 + k] = f2bf(v);
}

// ---------------- K0d: Wh -> packed bf16 [2 dir][4 sl][256 c][256 k] --------
__global__ void k_prep_wh(const float* __restrict__ Wh_f, const float* __restrict__ Wh_b,
                          unsigned short* __restrict__ WhP) {
    int row = blockIdx.x;          // 0..2047 = (d*4+sl)*256 + c
    int k = threadIdx.x;           // 0..255
    int d = row >> 10, sl = (row >> 8) & 3, c = row & 255;
    int gate = c >> 6, jrel = c & 63;
    const float* Wh = d ? Wh_b : Wh_f;
    WhP[(long)row * 256 + k] = f2bf(Wh[k * GF + gate * HID_ + sl * 64 + jrel]);
}

// ---------------- K0e: Wh gates i,f,o -> fp8 e4m3 [2 dir][3 g][256 j][256 k]-
__global__ void k_prep_wh8(const float* __restrict__ Wh_f, const float* __restrict__ Wh_b,
                           unsigned char* __restrict__ WhP8) {
    int row = blockIdx.x;          // 0..1535 = (d*3+gi)*256 + j
    int k = threadIdx.x;           // 0..255
    int d = row / 768, rr = row - d * 768, gi = rr >> 8, j = rr & 255;
    int ga = (gi == 2) ? 3 : gi;   // i=0, f=1, o=3
    const float* Wh = d ? Wh_b : Wh_f;
    float v = Wh[k * GF + ga * HID_ + j];
    int p = __builtin_amdgcn_cvt_pk_fp8_f32(v, 0.0f, 0, false);
    WhP8[(long)row * 256 + k] = (unsigned char)(p & 0xff);
}

// ---------------- K1: xz = X @ Wx + b  (MFMA, LDS-free) ---------------------
// xzP gate-major layout: u64 idx = ((s*16+g16)*64 + gate*16 + u16)*64 + b4*16 + j
// (u64 packs 4 batches b4*4+{0..3} as bf16). Producer stores are 512 B/wave
// contiguous; consumer reads stay 128 B/quad coalesced.
__global__ __launch_bounds__(256) void k_gemm_xz(
    const unsigned short* __restrict__ X16, const unsigned short* __restrict__ W16T,
    const float* __restrict__ b_f, const float* __restrict__ b_b,
    unsigned long long* __restrict__ xzP) {
    int w = threadIdx.x >> 6, lane = threadIdx.x & 63;
    int quad = lane >> 4, l16 = lane & 15;
    int m0 = blockIdx.x * 128 + w * 32;
    int n0 = blockIdx.y * 128;
    f32x4 acc[2][8];
#pragma unroll
    for (int mt = 0; mt < 2; ++mt)
#pragma unroll
        for (int nt = 0; nt < 8; ++nt) acc[mt][nt] = (f32x4){0.f, 0.f, 0.f, 0.f};

    int koff = quad * 8;
#pragma unroll
    for (int ks = 0; ks < 10; ++ks) {
        int k0 = ks * 32 + koff;
        bf16x8 a[2], bb[8];
#pragma unroll
        for (int mt = 0; mt < 2; ++mt)
            a[mt] = ldb8(X16 + (long)(m0 + mt * 16 + l16) * KPAD + k0);
#pragma unroll
        for (int nt = 0; nt < 8; ++nt)
            bb[nt] = ldb8(W16T + (long)(n0 + nt * 16 + l16) * KPAD + k0);
#pragma unroll
        for (int mt = 0; mt < 2; ++mt)
#pragma unroll
            for (int nt = 0; nt < 8; ++nt)
                acc[mt][nt] = __builtin_amdgcn_mfma_f32_16x16x32_bf16(a[mt], bb[nt], acc[mt][nt], 0, 0, 0);
    }
    int s = blockIdx.x;            // m>>7
#pragma unroll
    for (int mt = 0; mt < 2; ++mt) {
        int grp = w * 2 + mt;      // (b>>4)
#pragma unroll
        for (int nt = 0; nt < 8; ++nt) {
            int col = n0 + nt * 16 + l16;
            int dir = col >> 10, cc = col & 1023;
            int gate = cc >> 8, u16 = (cc & 255) >> 4;
            float bias = dir ? b_b[cc] : b_f[cc];
            unsigned long long pk = 0;
#pragma unroll
            for (int r = 0; r < 4; ++r)
                pk |= (unsigned long long)f2bf(acc[mt][nt][r] + bias) << (16 * r);
            long idx8 = ((long)(s * 16 + dir * 8 + grp)) * 4096 +
                        (gate * 16 + u16) * 64 + quad * 16 + l16;
            xzP[idx8] = pk;
        }
    }
}

// ---------------- K2: bidirectional LSTM recurrence, single-CU chains -------
// 64 blocks = 2 dir x 32 batch-groups(4). 512 threads, 2 waves/SIMD.
// Wh register-pinned: g bf16 (64 VGPR), i/f/o fp8 as K=128 scaled-MFMA
// fragments (96 VGPR; scale=1.0 => identical math to plain fp8 at 2x rate,
// 12 instead of 48 MFMA/wave/step). LDS = h double-buffers only. Barrier is
// hand-rolled "s_waitcnt lgkmcnt(0); s_barrier" — NO vmcnt drain, so hcat
// stores (register-direct) and xz prefetch stay in flight across steps.
// Round-2 changes vs the 673us baseline (structure reverted to baseline after
// the round-1 regression — acc-init/double-buffer caused spills + head-of-step
// vmcnt stalls):
//  - sigmoid via v_exp_f32 + v_rcp_f32 (kills 6 IEEE div expansions/lane/step,
//    two on the serial c/h chain).
//  - h pair packed with one v_cvt_pk_bf16_f32 + one paired cvt_pk_fp8.
__global__ __launch_bounds__(512, 2) void k_recurrence(
    const unsigned short* __restrict__ WhP, const unsigned char* __restrict__ WhP8,
    const unsigned long long* __restrict__ xzP, unsigned short* __restrict__ hcat16) {
    __shared__ __align__(16) unsigned char lds[6656];
    const int HB = 0, H8 = 4352;   // hb: 2 x 4 x 544 B; h8: 2 x 4 x 288 B
    int tid = threadIdx.x;
    int w = tid >> 6, lane = tid & 63, quad = lane >> 4, l16 = lane & 15;
    int blk = blockIdx.x;
    int d = blk >> 5, bg4 = blk & 31;
    int g16 = d * 8 + (bg4 >> 2), kq = bg4 & 3;
    int a3 = l16 & 3;

    // g-gate bf16 weight fragments, register-pinned (64 VGPR)
    u32x4 whg[2][8];
#pragma unroll
    for (int g2 = 0; g2 < 2; ++g2) {
        int j = 16 * (2 * w + g2) + l16;
        int sl = j >> 6, jrel = j & 63;
        const unsigned short* src = WhP + ((long)((d * 4 + sl) * 256 + 128 + jrel)) * 256;
#pragma unroll
        for (int kt = 0; kt < 8; ++kt) {
            u32x4 v = *reinterpret_cast<const u32x4*>(src + kt * 32 + quad * 8);
            asm volatile("" : "+v"(v));
            whg[g2][kt] = v;
        }
    }
    // i/f/o fp8 K=128 scaled-MFMA B fragments, register-pinned (96 VGPR)
    // B[k][n=l16], k = quad*32 + byte (32 contiguous bytes per lane)
    i32x8 wh8s[3][2][2];
#pragma unroll
    for (int gi = 0; gi < 3; ++gi)
#pragma unroll
        for (int g2 = 0; g2 < 2; ++g2)
#pragma unroll
            for (int kt2 = 0; kt2 < 2; ++kt2) {
                const unsigned char* wp8 = WhP8 +
                    ((long)((d * 3 + gi) * 256 + 16 * (2 * w + g2) + l16)) * 256 +
                    kt2 * 128 + quad * 32;
                i32x8 v = *reinterpret_cast<const i32x8*>(wp8);
                asm volatile("" : "+v"(v));
                wh8s[gi][g2][kt2] = v;
            }

    float c2[2] = {0.f, 0.f};
    int shq = 16 * quad;

    // preload xz for first step
    unsigned long long xz[2][4];
    {
        int s0 = d ? 255 : 0;
        long base = ((long)(s0 * 16 + g16)) * 4096;
#pragma unroll
        for (int g2 = 0; g2 < 2; ++g2)
#pragma unroll
            for (int ga = 0; ga < 4; ++ga)
                xz[g2][ga] = xzP[base + (ga * 16 + 2 * w + g2) * 64 + kq * 16 + l16];
    }

    for (int t = 0; t < 256; ++t) {
        int s = d ? (255 - t) : t;
        int pb = t & 1, cb = pb ^ 1;
        f32x4 accg[2];
        f32x4 acc8[3][2];
#pragma unroll
        for (int g2 = 0; g2 < 2; ++g2) {
            accg[g2] = (f32x4){0.f, 0.f, 0.f, 0.f};
#pragma unroll
            for (int gi = 0; gi < 3; ++gi) acc8[gi][g2] = (f32x4){0.f, 0.f, 0.f, 0.f};
        }

        if (t > 0) {
#pragma unroll
            for (int kt = 0; kt < 8; ++kt) {
                bf16x8 A = ldb8(reinterpret_cast<const unsigned short*>(
                    lds + HB + cb * 2176 + a3 * 544 + kt * 64 + quad * 16));
#pragma unroll
                for (int g2 = 0; g2 < 2; ++g2)
                    accg[g2] = __builtin_amdgcn_mfma_f32_16x16x32_bf16(
                        A, __builtin_bit_cast(bf16x8, whg[g2][kt]), accg[g2], 0, 0, 0);
            }
#pragma unroll
            for (int kt2 = 0; kt2 < 2; ++kt2) {
                i32x8 A8 = *reinterpret_cast<const i32x8*>(
                    lds + H8 + cb * 1152 + a3 * 288 + kt2 * 128 + quad * 32);
#pragma unroll
                for (int g2 = 0; g2 < 2; ++g2)
#pragma unroll
                    for (int gi = 0; gi < 3; ++gi)
#if __has_builtin(__builtin_amdgcn_mfma_scale_f32_16x16x128_f8f6f4)
                        acc8[gi][g2] = __builtin_amdgcn_mfma_scale_f32_16x16x128_f8f6f4(
                            A8, wh8s[gi][g2][kt2], acc8[gi][g2], 0, 0, 0, 0x7F, 0, 0x7F);
#else
                        acc8[gi][g2] = acc8[gi][g2];  // unreachable on gfx950
#endif
            }
        }
        // extract current-step xz addends, then immediately prefetch next step
        float xa[2][4];
#pragma unroll
        for (int g2 = 0; g2 < 2; ++g2)
#pragma unroll
            for (int ga = 0; ga < 4; ++ga) xa[g2][ga] = bfext(xz[g2][ga], shq);
        int sn = d ? (s ? s - 1 : 0) : (s < 255 ? s + 1 : 255);
        {
            long basen = ((long)(sn * 16 + g16)) * 4096;
#pragma unroll
            for (int g2 = 0; g2 < 2; ++g2)
#pragma unroll
                for (int ga = 0; ga < 4; ++ga)
                    xz[g2][ga] = xzP[basen + (ga * 16 + 2 * w + g2) * 64 + kq * 16 + l16];
        }
        // gates: lane (quad,l16) handles batch = bg4*4+quad, cols 16*(2w+g2)+l16
        float h0, h1;
        {
            float zi = selq(acc8[0][0], quad) + xa[0][0];
            float zf = selq(acc8[1][0], quad) + xa[0][1];
            float zg = selq(accg[0],    quad) + xa[0][2];
            float zo = selq(acc8[2][0], quad) + xa[0][3];
            float c = sigf(zf) * c2[0] + sigf(zi) * fmaxf(zg, 0.0f);
            c2[0] = c;
            h0 = sigf(zo) * fmaxf(c, 0.0f);
        }
        {
            float zi = selq(acc8[0][1], quad) + xa[1][0];
            float zf = selq(acc8[1][1], quad) + xa[1][1];
            float zg = selq(accg[1],    quad) + xa[1][2];
            float zo = selq(acc8[2][1], quad) + xa[1][3];
            float c = sigf(zf) * c2[1] + sigf(zi) * fmaxf(zg, 0.0f);
            c2[1] = c;
            h1 = sigf(zo) * fmaxf(c, 0.0f);
        }
        // pack h pair: one cvt_pk_bf16 + one paired cvt_pk_fp8 (addresses
        // identical to the per-g2 scalar stores of the baseline)
        unsigned int hbpk;
        asm("v_cvt_pk_bf16_f32 %0, %1, %2" : "=v"(hbpk) : "v"(h0), "v"(h1));
        unsigned short lo16 = (unsigned short)hbpk;
        unsigned short hi16 = (unsigned short)(hbpk >> 16);
        int col0 = 32 * w + l16;
        *reinterpret_cast<unsigned short*>(lds + HB + pb * 2176 + quad * 544 + col0 * 2)      = lo16;
        *reinterpret_cast<unsigned short*>(lds + HB + pb * 2176 + quad * 544 + col0 * 2 + 32) = hi16;
        int p8 = __builtin_amdgcn_cvt_pk_fp8_f32(h0, h1, 0, false);
        *(lds + H8 + pb * 1152 + quad * 288 + col0)      = (unsigned char)(p8 & 0xff);
        *(lds + H8 + pb * 1152 + quad * 288 + col0 + 16) = (unsigned char)((p8 >> 8) & 0xff);
        // hcat direct from register (fire-and-forget; barrier won't drain it)
        unsigned short* hc = hcat16 + ((long)(bg4 * 4 + quad) * S_ + s) * 512 + d * HID_ + col0;
        hc[0]  = lo16;
        hc[16] = hi16;
        // LDS-only barrier: no vmcnt drain (global stores/loads stay in flight)
        asm volatile("s_waitcnt lgkmcnt(0)\n\ts_barrier" ::: "memory");
    }
}

// ---------------- K3: logits = hcat @ Wd  (MFMA, N padded to 64) ------------
__global__ __launch_bounds__(256) void k_gemm_logits(
    const unsigned short* __restrict__ hcat16, const unsigned short* __restrict__ WdT16,
    float* __restrict__ logits) {
    int w = threadIdx.x >> 6, lane = threadIdx.x & 63;
    int quad = lane >> 4, l16 = lane & 15;
    int m0 = blockIdx.x * 128 + w * 32;
    f32x4 acc[2][4];
#pragma unroll
    for (int mt = 0; mt < 2; ++mt)
#pragma unroll
        for (int nt = 0; nt < 4; ++nt) acc[mt][nt] = (f32x4){0.f, 0.f, 0.f, 0.f};
#pragma unroll
    for (int ks = 0; ks < 16; ++ks) {
        int k0 = ks * 32 + quad * 8;
        bf16x8 a[2], bb[4];
#pragma unroll
        for (int mt = 0; mt < 2; ++mt)
            a[mt] = ldb8(hcat16 + (long)(m0 + mt * 16 + l16) * 512 + k0);
#pragma unroll
        for (int nt = 0; nt < 4; ++nt)
            bb[nt] = ldb8(WdT16 + (long)(nt * 16 + l16) * 512 + k0);
#pragma unroll
        for (int mt = 0; mt < 2; ++mt)
#pragma unroll
            for (int nt = 0; nt < 4; ++nt)
                acc[mt][nt] = __builtin_amdgcn_mfma_f32_16x16x32_bf16(a[mt], bb[nt], acc[mt][nt], 0, 0, 0);
    }
#pragma unroll
    for (int mt = 0; mt < 2; ++mt)
#pragma unroll
        for (int nt = 0; nt < 4; ++nt) {
            int rbase = m0 + mt * 16 + quad * 4;
            int col = nt * 16 + l16;
#pragma unroll
            for (int r = 0; r < 4; ++r)
                logits[(long)(rbase + r) * 64 + col] = acc[mt][nt][r];
        }
}

// ---------------- K4: +bd, softmax over 50 tags (one wave per row) ----------
__global__ __launch_bounds__(256) void k_softmax(const float* __restrict__ logits,
                                                 const float* __restrict__ bd,
                                                 float* __restrict__ out) {
    int w = threadIdx.x >> 6, lane = threadIdx.x & 63;
    long r = (long)blockIdx.x * 4 + w;
    float x = (lane < TAGS_) ? logits[r * 64 + lane] + bd[lane] : -3.0e38f;
    float m = x;
#pragma unroll
    for (int off = 32; off >= 1; off >>= 1) m = fmaxf(m, __shfl_xor(m, off, 64));
    float e = (lane < TAGS_) ? __expf(x - m) : 0.0f;
    float ssum = e;
#pragma unroll
    for (int off = 32; off >= 1; off >>= 1) ssum += __shfl_xor(ssum, off, 64);
    if (lane < TAGS_) out[r * TAGS_ + lane] = e / ssum;
}

extern "C" void kernel_launch(void* const* d_in, const int* in_sizes, int n_in,
                              void* d_out, int out_size, void* d_ws, size_t ws_size,
                              hipStream_t stream) {
    (void)in_sizes; (void)n_in; (void)out_size; (void)ws_size;
    const int*   tokens = (const int*)  d_in[0];
    const float* emb    = (const float*)d_in[1];
    const float* Wx_f   = (const float*)d_in[2];
    const float* Wh_f   = (const float*)d_in[3];
    const float* b_f    = (const float*)d_in[4];
    const float* Wx_b   = (const float*)d_in[5];
    const float* Wh_b   = (const float*)d_in[6];
    const float* b_b    = (const float*)d_in[7];
    const float* Wd     = (const float*)d_in[8];
    const float* bd     = (const float*)d_in[9];
    float* out = (float*)d_out;

    // workspace layout (bytes): total 190,119,936
    uint8_t* w = (uint8_t*)d_ws;
    unsigned short* X16    = (unsigned short*)(w);                  // 20,971,520 (dead after K1)
    // aliases inside X16's region, used only after K1:
    unsigned short* WhP    = (unsigned short*)(w);                  //  1,048,576
    unsigned char*  WhP8   = (unsigned char*)(w + 1048576);         //    393,216
    unsigned short* W16T   = (unsigned short*)(w + 20971520);       //  1,310,720
    unsigned short* WdT16  = (unsigned short*)(w + 22282240);       //     65,536
    unsigned long long* xzP = (unsigned long long*)(w + 22347776);  // 134,217,728
    unsigned short* hcat16 = (unsigned short*)(w + 156565504);      //  33,554,432
    float*          logits = (float*)(w + 22347776);                // alias xzP (dead after K2)

    k_gather_x  <<<dim3(NROWS),     dim3(KPAD), 0, stream>>>(tokens, emb, X16);
    k_prep_w    <<<dim3(NCOLS),     dim3(KPAD), 0, stream>>>(Wx_f, Wx_b, W16T);
    k_prep_wd   <<<dim3(64),        dim3(512),  0, stream>>>(Wd, WdT16);
    k_gemm_xz   <<<dim3(256, 16),   dim3(256),  0, stream>>>(X16, W16T, b_f, b_b, xzP);
    // X16 region now dead -> build WhP / WhP8 in it
    k_prep_wh   <<<dim3(2048),      dim3(256),  0, stream>>>(Wh_f, Wh_b, WhP);
    k_prep_wh8  <<<dim3(1536),      dim3(256),  0, stream>>>(Wh_f, Wh_b, WhP8);
    k_recurrence<<<dim3(64),        dim3(512),  0, stream>>>(WhP, WhP8, xzP, hcat16);
    k_gemm_logits<<<dim3(256),      dim3(256),  0, stream>>>(hcat16, WdT16, logits);
    k_softmax   <<<dim3(NROWS / 4), dim3(256),  0, stream>>>(logits, bd, out);
}

// Round 3
// 583.310 us; speedup vs baseline: 1.5022x; 1.0935x over previous
//
#include <hip/hip_runtime.h>
#include <stdint.h>

#define B_    128
#define S_    256
#define EMB_  300
#define HID_  256
#define TAGS_ 50
#define KPAD  320           // EMB padded to multiple of 32
#define NROWS (B_ * S_)     // 32768, row r = s*128 + b
#define GF    (4 * HID_)    // 1024 gate cols per direction
#define NCOLS (2 * GF)      // 2048 (fwd | bwd)

typedef __bf16 bf16x8 __attribute__((ext_vector_type(8)));
typedef float  f32x4  __attribute__((ext_vector_type(4)));
typedef unsigned int u32x4 __attribute__((ext_vector_type(4)));
typedef int    i32x8  __attribute__((ext_vector_type(8)));

__device__ __forceinline__ unsigned short f2bf(float f) {
    unsigned int u = __float_as_uint(f);
    unsigned int r = (u + 0x7fffu + ((u >> 16) & 1u)) >> 16;  // RNE
    return (unsigned short)r;
}
__device__ __forceinline__ bf16x8 ldb8(const unsigned short* p) {
    u32x4 v = *reinterpret_cast<const u32x4*>(p);
    return __builtin_bit_cast(bf16x8, v);
}
// fast sigmoid: v_exp_f32 + v_rcp_f32 (no IEEE div expansion; ~1ulp rcp err)
__device__ __forceinline__ float sigf(float x) {
    return __builtin_amdgcn_rcpf(1.0f + __builtin_amdgcn_exp2f(x * -1.44269504f));
}
// element (p) of an f32x4 pair-slot without dynamic vector indexing
__device__ __forceinline__ float sel2(f32x4 v, int p) {
    return p ? v[1] : v[0];   // rows {p, p+2} hold identical values; take p
}

// ---------------- K0a: embedding gather -> bf16, K-padded -------------------
__global__ void k_gather_x(const int* __restrict__ tokens, const float* __restrict__ emb,
                           unsigned short* __restrict__ X16) {
    int r = blockIdx.x;            // r = s*128 + b
    int k = threadIdx.x;           // 0..319
    int b = r & 127, s = r >> 7;
    int tok = tokens[b * S_ + s];
    float v = (k < EMB_) ? emb[(long)tok * EMB_ + k] : 0.0f;
    X16[(long)r * KPAD + k] = f2bf(v);
}

// ---------------- K0b: Wx (f|b) -> transposed bf16 [2048][320] --------------
__global__ void k_prep_w(const float* __restrict__ Wx_f, const float* __restrict__ Wx_b,
                         unsigned short* __restrict__ W16T) {
    int c = blockIdx.x;            // 0..2047
    int k = threadIdx.x;           // 0..319
    float v = 0.0f;
    if (k < EMB_) v = (c < GF) ? Wx_f[k * GF + c] : Wx_b[k * GF + (c - GF)];
    W16T[c * KPAD + k] = f2bf(v);
}

// ---------------- K0c: Wd -> transposed bf16 [64][512] ----------------------
__global__ void k_prep_wd(const float* __restrict__ Wd, unsigned short* __restrict__ WdT16) {
    int c = blockIdx.x;            // 0..63
    int k = threadIdx.x;           // 0..511
    float v = (c < TAGS_) ? Wd[k * TAGS_ + c] : 0.0f;
    WdT16[c * 512 + k] = f2bf(v);
}

// ---------------- K0d: Wh -> packed bf16 [2 dir][4 sl][256 c][256 k] --------
__global__ void k_prep_wh(const float* __restrict__ Wh_f, const float* __restrict__ Wh_b,
                          unsigned short* __restrict__ WhP) {
    int row = blockIdx.x;          // 0..2047 = (d*4+sl)*256 + c
    int k = threadIdx.x;           // 0..255
    int d = row >> 10, sl = (row >> 8) & 3, c = row & 255;
    int gate = c >> 6, jrel = c & 63;
    const float* Wh = d ? Wh_b : Wh_f;
    WhP[(long)row * 256 + k] = f2bf(Wh[k * GF + gate * HID_ + sl * 64 + jrel]);
}

// ---------------- K0e: Wh gates i,f,o -> fp8 e4m3 [2 dir][3 g][256 j][256 k]-
__global__ void k_prep_wh8(const float* __restrict__ Wh_f, const float* __restrict__ Wh_b,
                           unsigned char* __restrict__ WhP8) {
    int row = blockIdx.x;          // 0..1535 = (d*3+gi)*256 + j
    int k = threadIdx.x;           // 0..255
    int d = row / 768, rr = row - d * 768, gi = rr >> 8, j = rr & 255;
    int ga = (gi == 2) ? 3 : gi;   // i=0, f=1, o=3
    const float* Wh = d ? Wh_b : Wh_f;
    float v = Wh[k * GF + ga * HID_ + j];
    int p = __builtin_amdgcn_cvt_pk_fp8_f32(v, 0.0f, 0, false);
    WhP8[(long)row * 256 + k] = (unsigned char)(p & 0xff);
}

// ---------------- K1: xz = X @ Wx + b  (MFMA, LDS-free) ---------------------
// xzP gate-major layout: u64 idx = ((s*16+g16)*64 + gate*16 + u16)*64 + b4*16 + j
// (u64 packs 4 batches b4*4+{0..3} as bf16). Producer stores are 512 B/wave
// contiguous; consumer reads are per-lane ushort picks (see K2).
__global__ __launch_bounds__(256) void k_gemm_xz(
    const unsigned short* __restrict__ X16, const unsigned short* __restrict__ W16T,
    const float* __restrict__ b_f, const float* __restrict__ b_b,
    unsigned long long* __restrict__ xzP) {
    int w = threadIdx.x >> 6, lane = threadIdx.x & 63;
    int quad = lane >> 4, l16 = lane & 15;
    int m0 = blockIdx.x * 128 + w * 32;
    int n0 = blockIdx.y * 128;
    f32x4 acc[2][8];
#pragma unroll
    for (int mt = 0; mt < 2; ++mt)
#pragma unroll
        for (int nt = 0; nt < 8; ++nt) acc[mt][nt] = (f32x4){0.f, 0.f, 0.f, 0.f};

    int koff = quad * 8;
#pragma unroll
    for (int ks = 0; ks < 10; ++ks) {
        int k0 = ks * 32 + koff;
        bf16x8 a[2], bb[8];
#pragma unroll
        for (int mt = 0; mt < 2; ++mt)
            a[mt] = ldb8(X16 + (long)(m0 + mt * 16 + l16) * KPAD + k0);
#pragma unroll
        for (int nt = 0; nt < 8; ++nt)
            bb[nt] = ldb8(W16T + (long)(n0 + nt * 16 + l16) * KPAD + k0);
#pragma unroll
        for (int mt = 0; mt < 2; ++mt)
#pragma unroll
            for (int nt = 0; nt < 8; ++nt)
                acc[mt][nt] = __builtin_amdgcn_mfma_f32_16x16x32_bf16(a[mt], bb[nt], acc[mt][nt], 0, 0, 0);
    }
    int s = blockIdx.x;            // m>>7
#pragma unroll
    for (int mt = 0; mt < 2; ++mt) {
        int grp = w * 2 + mt;      // (b>>4)
#pragma unroll
        for (int nt = 0; nt < 8; ++nt) {
            int col = n0 + nt * 16 + l16;
            int dir = col >> 10, cc = col & 1023;
            int gate = cc >> 8, u16 = (cc & 255) >> 4;
            float bias = dir ? b_b[cc] : b_f[cc];
            unsigned long long pk = 0;
#pragma unroll
            for (int r = 0; r < 4; ++r)
                pk |= (unsigned long long)f2bf(acc[mt][nt][r] + bias) << (16 * r);
            long idx8 = ((long)(s * 16 + dir * 8 + grp)) * 4096 +
                        (gate * 16 + u16) * 64 + quad * 16 + l16;
            xzP[idx8] = pk;
        }
    }
}

// ---------------- K2: bidirectional LSTM recurrence, single-CU chains -------
// Round-3 restructure: 128 blocks = 2 dir x 64 batch-PAIRS (was 64 blocks x
// 4 batches). Rationale (rocprof): MfmaUtil==VALUBusy==~45% active-CU => the
// MFMA phase and VALU phase SUM per step (true dependency chain through the
// barrier). Per-SIMD MFMA issue cycles are invariant to batches/block (M-
// replication absorbs it: always 224 MFMA/block-step), but VALU scales with
// batches/block. Halving batches/block halves the VALU phase and doubles
// active CUs (wall time = 256*step, so only step time matters).
//   - lane owns ONE cell: batch parity p=quad&1, colgroup cg=quad>>1,
//     col=16*(2w+cg)+l16. A-rows map batch=row&1 so the needed C element is
//     at compile-time-parity position (1 cndmask; selq chains gone).
//   - xz fetched as 4 global_load_ushort per lane (no 64-bit bfext shifts).
//   - Wh fragments, barrier (lgkmcnt-only, no vmcnt drain), prefetch position
//     unchanged from the verified 298us kernel.
__global__ __launch_bounds__(512, 2) void k_recurrence(
    const unsigned short* __restrict__ WhP, const unsigned char* __restrict__ WhP8,
    const unsigned long long* __restrict__ xzP, unsigned short* __restrict__ hcat16) {
    __shared__ __align__(16) unsigned char lds[3328];
    const int HB = 0, H8 = 2176;   // hb: 2 x 2 x 544 B; h8: 2 x 2 x 288 B
    int tid = threadIdx.x;
    int w = tid >> 6, lane = tid & 63, quad = lane >> 4, l16 = lane & 15;
    int blk = blockIdx.x;
    int d = blk >> 6, bg2 = blk & 63;           // batch pair b0 = bg2*2
    int p = quad & 1;                            // lane's batch parity
    int cg = quad >> 1;                          // lane's colgroup (0/1)
    int col = 16 * (2 * w + cg) + l16;           // lane's cell column
    int rp = l16 & 1;                            // A-row parity of this lane's row

    // g-gate bf16 weight fragments, register-pinned (64 VGPR) — both colgroups
    u32x4 whg[2][8];
#pragma unroll
    for (int cgi = 0; cgi < 2; ++cgi) {
        int j = 16 * (2 * w + cgi) + l16;
        int sl = j >> 6, jrel = j & 63;
        const unsigned short* src = WhP + ((long)((d * 4 + sl) * 256 + 128 + jrel)) * 256;
#pragma unroll
        for (int kt = 0; kt < 8; ++kt) {
            u32x4 v = *reinterpret_cast<const u32x4*>(src + kt * 32 + quad * 8);
            asm volatile("" : "+v"(v));
            whg[cgi][kt] = v;
        }
    }
    // i/f/o fp8 K=128 scaled-MFMA B fragments, register-pinned (96 VGPR)
    i32x8 wh8s[3][2][2];
#pragma unroll
    for (int gi = 0; gi < 3; ++gi)
#pragma unroll
        for (int cgi = 0; cgi < 2; ++cgi)
#pragma unroll
            for (int kt2 = 0; kt2 < 2; ++kt2) {
                const unsigned char* wp8 = WhP8 +
                    ((long)((d * 3 + gi) * 256 + 16 * (2 * w + cgi) + l16)) * 256 +
                    kt2 * 128 + quad * 32;
                i32x8 v = *reinterpret_cast<const i32x8*>(wp8);
                asm volatile("" : "+v"(v));
                wh8s[gi][cgi][kt2] = v;
            }

    float c2 = 0.f;

    // xz addressing: u16 index = (s*16 + rowc)*16384 + ga*4096 + laneoff
    // (derived from K1's u64 layout; b = bg2*2+p, col = 16*(2w+cg)+l16)
    const unsigned short* xzU = (const unsigned short*)xzP;
    int rowc = d * 8 + (bg2 >> 3);
    unsigned int laneoff = (unsigned)((2 * w + cg) * 256 +
                                      (((bg2 >> 1) & 3) * 16 + l16) * 4 +
                                      2 * (bg2 & 1) + p);

    // preload xz for first step (4 ushorts per lane: gates i,f,g,o)
    unsigned short xzu[4];
    {
        int s0 = d ? 255 : 0;
        const unsigned short* ps = xzU + (unsigned long)(s0 * 16 + rowc) * 16384;
#pragma unroll
        for (int ga = 0; ga < 4; ++ga) xzu[ga] = ps[laneoff + ga * 4096];
    }

    for (int t = 0; t < 256; ++t) {
        int s = d ? (255 - t) : t;
        int pb = t & 1, cb = pb ^ 1;
        f32x4 accg[2];
        f32x4 acc8[3][2];
#pragma unroll
        for (int cgi = 0; cgi < 2; ++cgi) {
            accg[cgi] = (f32x4){0.f, 0.f, 0.f, 0.f};
#pragma unroll
            for (int gi = 0; gi < 3; ++gi) acc8[gi][cgi] = (f32x4){0.f, 0.f, 0.f, 0.f};
        }

        if (t > 0) {
#pragma unroll
            for (int kt = 0; kt < 8; ++kt) {
                // A row l16 -> batch l16&1 (rows r and r+2 identical)
                bf16x8 A = ldb8(reinterpret_cast<const unsigned short*>(
                    lds + HB + cb * 1088 + rp * 544 + kt * 64 + quad * 16));
#pragma unroll
                for (int cgi = 0; cgi < 2; ++cgi)
                    accg[cgi] = __builtin_amdgcn_mfma_f32_16x16x32_bf16(
                        A, __builtin_bit_cast(bf16x8, whg[cgi][kt]), accg[cgi], 0, 0, 0);
            }
#pragma unroll
            for (int kt2 = 0; kt2 < 2; ++kt2) {
                i32x8 A8 = *reinterpret_cast<const i32x8*>(
                    lds + H8 + cb * 576 + rp * 288 + kt2 * 128 + quad * 32);
#pragma unroll
                for (int cgi = 0; cgi < 2; ++cgi)
#pragma unroll
                    for (int gi = 0; gi < 3; ++gi)
#if __has_builtin(__builtin_amdgcn_mfma_scale_f32_16x16x128_f8f6f4)
                        acc8[gi][cgi] = __builtin_amdgcn_mfma_scale_f32_16x16x128_f8f6f4(
                            A8, wh8s[gi][cgi][kt2], acc8[gi][cgi], 0, 0, 0, 0x7F, 0, 0x7F);
#else
                        acc8[gi][cgi] = acc8[gi][cgi];  // unreachable on gfx950
#endif
            }
        }
        // extract current-step xz addends (bf16 -> f32 is one shl each)
        float xa0 = __uint_as_float((unsigned int)xzu[0] << 16);
        float xa1 = __uint_as_float((unsigned int)xzu[1] << 16);
        float xa2 = __uint_as_float((unsigned int)xzu[2] << 16);
        float xa3 = __uint_as_float((unsigned int)xzu[3] << 16);
        // prefetch next step (fire-and-forget; consumed after next barrier)
        {
            int sn = d ? (s ? s - 1 : 0) : (s < 255 ? s + 1 : 255);
            const unsigned short* ps = xzU + (unsigned long)(sn * 16 + rowc) * 16384;
#pragma unroll
            for (int ga = 0; ga < 4; ++ga) xzu[ga] = ps[laneoff + ga * 4096];
        }
        // gates: lane's cell (batch bg2*2+p, col). C row m=quad*4+r has batch
        // m&1=r&1 -> element p (== element p+2). Colgroup pick by cg.
        float zi = (cg ? sel2(acc8[0][1], p) : sel2(acc8[0][0], p)) + xa0;
        float zf = (cg ? sel2(acc8[1][1], p) : sel2(acc8[1][0], p)) + xa1;
        float zg = (cg ? sel2(accg[1],    p) : sel2(accg[0],    p)) + xa2;
        float zo = (cg ? sel2(acc8[2][1], p) : sel2(acc8[2][0], p)) + xa3;
        float c = sigf(zf) * c2 + sigf(zi) * fmaxf(zg, 0.0f);
        c2 = c;
        float h = sigf(zo) * fmaxf(c, 0.0f);

        unsigned short hb16 = f2bf(h);
        *reinterpret_cast<unsigned short*>(lds + HB + pb * 1088 + p * 544 + col * 2) = hb16;
        int p8 = __builtin_amdgcn_cvt_pk_fp8_f32(h, h, 0, false);
        *(lds + H8 + pb * 576 + p * 288 + col) = (unsigned char)(p8 & 0xff);
        // hcat direct from register (fire-and-forget; barrier won't drain it)
        hcat16[((long)(bg2 * 2 + p) * S_ + s) * 512 + d * HID_ + col] = hb16;
        // LDS-only barrier: no vmcnt drain (global stores/loads stay in flight)
        asm volatile("s_waitcnt lgkmcnt(0)\n\ts_barrier" ::: "memory");
    }
}

// ---------------- K3: logits = hcat @ Wd  (MFMA, N padded to 64) ------------
__global__ __launch_bounds__(256) void k_gemm_logits(
    const unsigned short* __restrict__ hcat16, const unsigned short* __restrict__ WdT16,
    float* __restrict__ logits) {
    int w = threadIdx.x >> 6, lane = threadIdx.x & 63;
    int quad = lane >> 4, l16 = lane & 15;
    int m0 = blockIdx.x * 128 + w * 32;
    f32x4 acc[2][4];
#pragma unroll
    for (int mt = 0; mt < 2; ++mt)
#pragma unroll
        for (int nt = 0; nt < 4; ++nt) acc[mt][nt] = (f32x4){0.f, 0.f, 0.f, 0.f};
#pragma unroll
    for (int ks = 0; ks < 16; ++ks) {
        int k0 = ks * 32 + quad * 8;
        bf16x8 a[2], bb[4];
#pragma unroll
        for (int mt = 0; mt < 2; ++mt)
            a[mt] = ldb8(hcat16 + (long)(m0 + mt * 16 + l16) * 512 + k0);
#pragma unroll
        for (int nt = 0; nt < 4; ++nt)
            bb[nt] = ldb8(WdT16 + (long)(nt * 16 + l16) * 512 + k0);
#pragma unroll
        for (int mt = 0; mt < 2; ++mt)
#pragma unroll
            for (int nt = 0; nt < 4; ++nt)
                acc[mt][nt] = __builtin_amdgcn_mfma_f32_16x16x32_bf16(a[mt], bb[nt], acc[mt][nt], 0, 0, 0);
    }
#pragma unroll
    for (int mt = 0; mt < 2; ++mt)
#pragma unroll
        for (int nt = 0; nt < 4; ++nt) {
            int rbase = m0 + mt * 16 + quad * 4;
            int col = nt * 16 + l16;
#pragma unroll
            for (int r = 0; r < 4; ++r)
                logits[(long)(rbase + r) * 64 + col] = acc[mt][nt][r];
        }
}

// ---------------- K4: +bd, softmax over 50 tags (one wave per row) ----------
__global__ __launch_bounds__(256) void k_softmax(const float* __restrict__ logits,
                                                 const float* __restrict__ bd,
                                                 float* __restrict__ out) {
    int w = threadIdx.x >> 6, lane = threadIdx.x & 63;
    long r = (long)blockIdx.x * 4 + w;
    float x = (lane < TAGS_) ? logits[r * 64 + lane] + bd[lane] : -3.0e38f;
    float m = x;
#pragma unroll
    for (int off = 32; off >= 1; off >>= 1) m = fmaxf(m, __shfl_xor(m, off, 64));
    float e = (lane < TAGS_) ? __expf(x - m) : 0.0f;
    float ssum = e;
#pragma unroll
    for (int off = 32; off >= 1; off >>= 1) ssum += __shfl_xor(ssum, off, 64);
    if (lane < TAGS_) out[r * TAGS_ + lane] = e / ssum;
}

extern "C" void kernel_launch(void* const* d_in, const int* in_sizes, int n_in,
                              void* d_out, int out_size, void* d_ws, size_t ws_size,
                              hipStream_t stream) {
    (void)in_sizes; (void)n_in; (void)out_size; (void)ws_size;
    const int*   tokens = (const int*)  d_in[0];
    const float* emb    = (const float*)d_in[1];
    const float* Wx_f   = (const float*)d_in[2];
    const float* Wh_f   = (const float*)d_in[3];
    const float* b_f    = (const float*)d_in[4];
    const float* Wx_b   = (const float*)d_in[5];
    const float* Wh_b   = (const float*)d_in[6];
    const float* b_b    = (const float*)d_in[7];
    const float* Wd     = (const float*)d_in[8];
    const float* bd     = (const float*)d_in[9];
    float* out = (float*)d_out;

    // workspace layout (bytes): total 190,119,936
    uint8_t* w = (uint8_t*)d_ws;
    unsigned short* X16    = (unsigned short*)(w);                  // 20,971,520 (dead after K1)
    // aliases inside X16's region, used only after K1:
    unsigned short* WhP    = (unsigned short*)(w);                  //  1,048,576
    unsigned char*  WhP8   = (unsigned char*)(w + 1048576);         //    393,216
    unsigned short* W16T   = (unsigned short*)(w + 20971520);       //  1,310,720
    unsigned short* WdT16  = (unsigned short*)(w + 22282240);       //     65,536
    unsigned long long* xzP = (unsigned long long*)(w + 22347776);  // 134,217,728
    unsigned short* hcat16 = (unsigned short*)(w + 156565504);      //  33,554,432
    float*          logits = (float*)(w + 22347776);                // alias xzP (dead after K2)

    k_gather_x  <<<dim3(NROWS),     dim3(KPAD), 0, stream>>>(tokens, emb, X16);
    k_prep_w    <<<dim3(NCOLS),     dim3(KPAD), 0, stream>>>(Wx_f, Wx_b, W16T);
    k_prep_wd   <<<dim3(64),        dim3(512),  0, stream>>>(Wd, WdT16);
    k_gemm_xz   <<<dim3(256, 16),   dim3(256),  0, stream>>>(X16, W16T, b_f, b_b, xzP);
    // X16 region now dead -> build WhP / WhP8 in it
    k_prep_wh   <<<dim3(2048),      dim3(256),  0, stream>>>(Wh_f, Wh_b, WhP);
    k_prep_wh8  <<<dim3(1536),      dim3(256),  0, stream>>>(Wh_f, Wh_b, WhP8);
    k_recurrence<<<dim3(128),       dim3(512),  0, stream>>>(WhP, WhP8, xzP, hcat16);
    k_gemm_logits<<<dim3(256),      dim3(256),  0, stream>>>(hcat16, WdT16, logits);
    k_softmax   <<<dim3(NROWS / 4), dim3(256),  0, stream>>>(logits, bd, out);
}